// Round 6
// baseline (218.381 us; speedup 1.0000x reference)
//
#include <hip/hip_runtime.h>
#include <math.h>

#define NN 768
#define DD 128
#define AA 312
#define HH 8
#define CEPS 1e-8f

typedef __attribute__((ext_vector_type(2))) float v2f;

__device__ __forceinline__ v2f vfma2(v2f a, v2f b, v2f c) {
#if __has_builtin(__builtin_elementwise_fma)
    return __builtin_elementwise_fma(a, b, c);
#else
    v2f r;
    r.x = fmaf(a.x, b.x, c.x);
    r.y = fmaf(a.y, b.y, c.y);
    return r;
#endif
}

__device__ __forceinline__ float wave_sum(float v) {
    #pragma unroll
    for (int o = 32; o; o >>= 1) v += __shfl_down(v, o, 64);
    return v;
}
__device__ __forceinline__ float wave_max(float v) {
    #pragma unroll
    for (int o = 32; o; o >>= 1) v = fmaxf(v, __shfl_down(v, o, 64));
    return v;
}

// ---------------- K1: gram logits (inline row norms, pk math) + W transposes ----------------
template <int COLS>
__device__ void gram_tile(const float* __restrict__ A, float invtemp, float* __restrict__ sim,
                          int i0, int j0, int tid, float* As, float* Bs) {
    const int tx = tid & 15, ty = tid >> 4;
    const int lr = tid >> 3, lc4 = (tid & 7) * 4;
    v2f acc0 = {0.f, 0.f}, acc1 = {0.f, 0.f};  // {i0j0,i0j1}, {i1j0,i1j1}
    v2f si = {0.f, 0.f}, sj = {0.f, 0.f};
    for (int kc = 0; kc < COLS; kc += 32) {
        float4 av, bv;
        if (kc + lc4 + 4 <= COLS) {
            av = *(const float4*)(A + (size_t)(i0 + lr) * COLS + kc + lc4);
            bv = *(const float4*)(A + (size_t)(j0 + lr) * COLS + kc + lc4);
        } else {
            float ta[4], tb[4];
            #pragma unroll
            for (int l = 0; l < 4; ++l) {
                int c = kc + lc4 + l;
                ta[l] = (c < COLS) ? A[(size_t)(i0 + lr) * COLS + c] : 0.f;
                tb[l] = (c < COLS) ? A[(size_t)(j0 + lr) * COLS + c] : 0.f;
            }
            av = make_float4(ta[0], ta[1], ta[2], ta[3]);
            bv = make_float4(tb[0], tb[1], tb[2], tb[3]);
        }
        __syncthreads();
        As[(lc4 + 0) * 34 + lr] = av.x; As[(lc4 + 1) * 34 + lr] = av.y;
        As[(lc4 + 2) * 34 + lr] = av.z; As[(lc4 + 3) * 34 + lr] = av.w;
        Bs[(lc4 + 0) * 34 + lr] = bv.x; Bs[(lc4 + 1) * 34 + lr] = bv.y;
        Bs[(lc4 + 2) * 34 + lr] = bv.z; Bs[(lc4 + 3) * 34 + lr] = bv.w;
        __syncthreads();
        #pragma unroll
        for (int k = 0; k < 32; ++k) {
            const v2f a = *(const v2f*)&As[k * 34 + 2 * ty];
            const v2f b = *(const v2f*)&Bs[k * 34 + 2 * tx];
            v2f ax; ax.x = a.x; ax.y = a.x;
            v2f ay; ay.x = a.y; ay.y = a.y;
            acc0 = vfma2(ax, b, acc0);
            acc1 = vfma2(ay, b, acc1);
            si = vfma2(a, a, si);
            sj = vfma2(b, b, sj);
        }
    }
    const float ni0 = sqrtf(si.x), ni1 = sqrtf(si.y);
    const float nj0 = sqrtf(sj.x), nj1 = sqrtf(sj.y);
    float* s0 = sim + (size_t)(i0 + 2 * ty) * NN + j0 + 2 * tx;
    float* s1 = s0 + NN;
    s0[0] = acc0.x / fmaxf(ni0 * nj0, CEPS) * invtemp;
    s0[1] = acc0.y / fmaxf(ni0 * nj1, CEPS) * invtemp;
    s1[0] = acc1.x / fmaxf(ni1 * nj0, CEPS) * invtemp;
    s1[1] = acc1.y / fmaxf(ni1 * nj1, CEPS) * invtemp;
}

__global__ __launch_bounds__(256) void gram_prep_kernel(
    const float* __restrict__ visual, const float* __restrict__ attribute,
    const float* __restrict__ Wvn, const float* __restrict__ Wsn, float* __restrict__ simv,
    float* __restrict__ sima, float* __restrict__ WvnT, float* __restrict__ WsnT) {
    __shared__ __align__(16) float smem[2176];
    const int tid = threadIdx.x;
    const int task = blockIdx.x;
    if (task < 576) {
        gram_tile<DD>(visual, 10.f, simv, (task / 24) * 32, (task % 24) * 32, tid, smem,
                      smem + 1088);
    } else if (task < 1152) {
        const int rem = task - 576;
        gram_tile<AA>(attribute, 10.f, sima, (rem / 24) * 32, (rem % 24) * 32, tid, smem,
                      smem + 1088);
    } else {
        const int u = task - 1152;
        const float* S = (u >= 16) ? Wsn : Wvn;
        float* Dt = (u >= 16) ? WsnT : WvnT;
        const int tile = u & 15;
        const int c0 = (tile & 3) * 32, r0 = (tile >> 2) * 32;
        const int tx = tid & 31, ty = tid >> 5;
        #pragma unroll
        for (int rr = ty; rr < 32; rr += 8)
            smem[rr * 33 + tx] = S[(size_t)(r0 + rr) * DD + c0 + tx];
        __syncthreads();
        #pragma unroll
        for (int rr = ty; rr < 32; rr += 8)
            Dt[(size_t)(c0 + rr) * DD + r0 + tx] = smem[tx * 33 + rr];
    }
}

// block-wide softmax (512 threads) over a 768-float LDS buffer, in place.
__device__ void block_softmax768(float* buf, int tid, float* red) {
    const int w = tid >> 6, lane = tid & 63;
    float v0 = buf[tid];
    float v1 = (tid < NN - 512) ? buf[tid + 512] : -3.4e38f;
    float m = wave_max(fmaxf(v0, v1));
    if (lane == 0) red[w] = m;
    __syncthreads();
    m = red[0];
    #pragma unroll
    for (int i = 1; i < 8; ++i) m = fmaxf(m, red[i]);
    float e0 = __expf(v0 - m);
    float e1 = (tid < NN - 512) ? __expf(v1 - m) : 0.f;
    float sw = wave_sum(e0 + e1);
    if (lane == 0) red[8 + w] = sw;
    __syncthreads();
    float s = 0.f;
    #pragma unroll
    for (int i = 0; i < 8; ++i) s += red[8 + i];
    const float inv = 1.f / s;
    buf[tid] = e0 * inv;
    if (tid < NN - 512) buf[tid + 512] = e1 * inv;
    __syncthreads();
}

// softmax of a global 768-row into an LDS buffer (384 threads, 2 cols/thread).
__device__ void softmax_row_to384(const float* __restrict__ vr, float* __restrict__ dst,
                                  int tid, float* red) {
    float v0 = vr[tid], v1 = vr[tid + 384];
    float m = wave_max(fmaxf(v0, v1));
    if ((tid & 63) == 0) red[tid >> 6] = m;
    __syncthreads();
    m = red[0];
    #pragma unroll
    for (int i = 1; i < 6; ++i) m = fmaxf(m, red[i]);
    float e0 = __expf(v0 - m), e1 = __expf(v1 - m);
    float sw = wave_sum(e0 + e1);
    if ((tid & 63) == 0) red[8 + (tid >> 6)] = sw;
    __syncthreads();
    float s = 0.f;
    #pragma unroll
    for (int i = 0; i < 6; ++i) s += red[8 + i];
    const float inv = 1.f / s;
    dst[tid] = e0 * inv;
    dst[tid + 384] = e1 * inv;
    __syncthreads();
}

// ---------------- K2: node1 (vp), softmax-on-the-fly, packed-f32 ----------------
__global__ __launch_bounds__(512) void node1_kernel(
    const float* __restrict__ P, const float* __restrict__ srcEp,
    const float* __restrict__ srcEx, const float* __restrict__ WT, const float* __restrict__ b,
    const float* __restrict__ g, const float* __restrict__ beta, float* __restrict__ out,
    float* __restrict__ outT) {
    __shared__ __align__(16) float ep[2][NN], ex[2][NN];
    __shared__ __align__(16) float pp[4][2][DD], xx[4][2][DD];
    __shared__ __align__(16) float qs[2][DD], tps[2][2][DD];
    __shared__ float red[16];
    const int i0 = blockIdx.x * 2;
    const int tid = threadIdx.x;
    const int s = (tid >> 7) & 3, d = tid & 127;
    #pragma unroll
    for (int r = 0; r < 2; ++r)
        for (int k = tid; k < NN; k += 512) {
            ep[r][k] = srcEp[(size_t)(i0 + r) * NN + k];
            ex[r][k] = srcEx[(size_t)(i0 + r) * NN + k];
        }
    __syncthreads();
    block_softmax768(ep[0], tid, red);
    block_softmax768(ep[1], tid, red);
    block_softmax768(ex[0], tid, red);
    block_softmax768(ex[1], tid, red);
    v2f P0 = {0.f, 0.f}, X0 = {0.f, 0.f}, P1 = {0.f, 0.f}, X1 = {0.f, 0.f};
    const int kb = s * 192;
    #pragma unroll 4
    for (int kk = 0; kk < 192; kk += 2) {
        const int k = kb + kk;
        v2f pv; pv.x = P[(size_t)k * DD + d]; pv.y = P[(size_t)(k + 1) * DD + d];
        const v2f e0v = *(const v2f*)&ep[0][k];
        const v2f x0v = *(const v2f*)&ex[0][k];
        const v2f e1v = *(const v2f*)&ep[1][k];
        const v2f x1v = *(const v2f*)&ex[1][k];
        P0 = vfma2(e0v, pv, P0);
        X0 = vfma2(x0v, pv, X0);
        P1 = vfma2(e1v, pv, P1);
        X1 = vfma2(x1v, pv, X1);
    }
    pp[s][0][d] = P0.x + P0.y; xx[s][0][d] = X0.x + X0.y;
    pp[s][1][d] = P1.x + P1.y; xx[s][1][d] = X1.x + X1.y;
    __syncthreads();
    const int rr = (tid >> 7) & 1;
    float preg = 0.f;
    if (tid < 256) {
        float p = pp[0][rr][d] + pp[1][rr][d] + pp[2][rr][d] + pp[3][rr][d];
        float x = xx[0][rr][d] + xx[1][rr][d] + xx[2][rr][d] + xx[3][rr][d];
        qs[rr][d] = p + x;
        preg = p;
    }
    __syncthreads();
    {
        const int sc = tid >> 8, rr2 = (tid >> 7) & 1;
        v2f acc; acc.x = (sc == 0) ? b[d] : 0.f; acc.y = 0.f;
        const int c0 = sc * 64;
        #pragma unroll 4
        for (int c = c0; c < c0 + 64; c += 2) {
            v2f wv; wv.x = WT[(size_t)c * DD + d]; wv.y = WT[(size_t)(c + 1) * DD + d];
            const v2f qq = *(const v2f*)&qs[rr2][c];
            acc = vfma2(qq, wv, acc);
        }
        tps[sc][rr2][d] = acc.x + acc.y;
    }
    __syncthreads();
    float tval = 0.f;
    if (tid < 256) tval = tps[0][rr][d] + tps[1][rr][d];
    float sm = wave_sum(tid < 256 ? tval : 0.f);
    if ((tid & 63) == 0) red[tid >> 6] = sm;
    __syncthreads();
    if (tid < 256) tval -= (red[2 * rr] + red[2 * rr + 1]) * (1.f / DD);
    float s2 = wave_sum(tid < 256 ? tval * tval : 0.f);
    if ((tid & 63) == 0) red[8 + (tid >> 6)] = s2;
    __syncthreads();
    if (tid < 256) {
        const float var = (red[8 + 2 * rr] + red[8 + 2 * rr + 1]) * (1.f / DD);
        const float ln = tval * rsqrtf(var + 1e-5f) * g[d] + beta[d];
        const float val = fmaxf(ln, 0.f) + preg;
        out[(size_t)(i0 + rr) * DD + d] = val;
        outT[(size_t)d * NN + i0 + rr] = val;
    }
}

__device__ __forceinline__ float edge_mlp_tail(float* z, const float* __restrict__ b1,
                                               const float* __restrict__ W2, float b2s) {
    float mean = 0.f;
    #pragma unroll
    for (int r = 0; r < HH; ++r) { z[r] += b1[r]; mean += z[r]; }
    mean *= (1.f / HH);
    float var = 0.f;
    #pragma unroll
    for (int r = 0; r < HH; ++r) { float dv = z[r] - mean; var += dv * dv; }
    var *= (1.f / HH);
    const float istd = rsqrtf(var + 1e-5f);
    float acc = b2s;
    #pragma unroll
    for (int r = 0; r < HH; ++r) {
        float hn = fmaxf((z[r] - mean) * istd, 0.f);
        acc = fmaf(hn, W2[r], acc);
    }
    return tanhf(acc);
}

// ---------------- K3/K4: edge update, 384 thr, float2 j-groups, packed-f32 ----------------
// FUSE: block i also computes sp row i = relu(LN((se_i@S + ve2_i@S)@Wsn^T + b)) + se_i@S.
template <bool FUSE>
__global__ __launch_bounds__(384) void edge_fused_kernel(
    const float* __restrict__ PR, const float* __restrict__ PRt,
    const float* __restrict__ lastSim, const float* __restrict__ W1,
    const float* __restrict__ b1, const float* __restrict__ W2, const float* __restrict__ b2,
    float invtemp, float* __restrict__ E2,
    // node-fusion args
    const float* __restrict__ simaRows, const float* __restrict__ S,
    const float* __restrict__ WT, const float* __restrict__ nb, const float* __restrict__ ng,
    const float* __restrict__ nbeta, float* __restrict__ outN, float* __restrict__ outNT) {
    const int i = blockIdx.x;
    const int tid = threadIdx.x;
    __shared__ __align__(16) float pi[DD];
    __shared__ __align__(16) float4 w_s[HH][DD / 4];
    __shared__ __align__(16) float lrow[NN];
    __shared__ __align__(16) float aux[NN];     // se row (FUSE)
    __shared__ __align__(16) float ve2row[NN];  // ve2 row (FUSE)
    __shared__ __align__(16) float partp[3][DD], partx[3][DD];
    __shared__ __align__(16) float qvv[DD];
    __shared__ float red[16];
    if (tid < DD) pi[tid] = PR[(size_t)i * DD + tid];
    if (tid < 256) ((float4*)w_s)[tid] = ((const float4*)W1)[tid];
    softmax_row_to384(lastSim + (size_t)i * NN, lrow, tid, red);  // includes syncthreads
    if (FUSE) softmax_row_to384(simaRows + (size_t)i * NN, aux, tid, red);
    const int j0 = tid * 2;
    v2f zz0[HH], zz1[HH];
    #pragma unroll
    for (int r = 0; r < HH; ++r) { zz0[r] = (v2f){0.f, 0.f}; zz1[r] = (v2f){0.f, 0.f}; }
    const float4* p4 = (const float4*)pi;
    #pragma unroll 2
    for (int k4 = 0; k4 < DD / 4; ++k4) {
        const float4 pv4 = p4[k4];
        const float* r0 = PRt + (size_t)(k4 * 4) * NN;
        const float2 f0 = *(const float2*)&r0[j0];
        const float2 f1 = *(const float2*)&r0[NN + j0];
        const float2 f2 = *(const float2*)&r0[2 * NN + j0];
        const float2 f3 = *(const float2*)&r0[3 * NN + j0];
        v2f pa; pa.x = pv4.x; pa.y = pv4.y;
        v2f pb; pb.x = pv4.z; pb.y = pv4.w;
        v2f ja0; ja0.x = f0.x; ja0.y = f1.x;
        v2f jb0; jb0.x = f2.x; jb0.y = f3.x;
        v2f ja1; ja1.x = f0.y; ja1.y = f1.y;
        v2f jb1; jb1.x = f2.y; jb1.y = f3.y;
        const v2f da0 = pa - ja0, db0 = pb - jb0;
        const v2f da1 = pa - ja1, db1 = pb - jb1;
        const v2f sa0 = da0 * da0, sb0 = db0 * db0;
        const v2f sa1 = da1 * da1, sb1 = db1 * db1;
        #pragma unroll
        for (int r = 0; r < HH; ++r) {
            const float4 w = w_s[r][k4];
            v2f wa; wa.x = w.x; wa.y = w.y;
            v2f wb; wb.x = w.z; wb.y = w.w;
            zz0[r] = vfma2(wa, sa0, zz0[r]); zz0[r] = vfma2(wb, sb0, zz0[r]);
            zz1[r] = vfma2(wa, sa1, zz1[r]); zz1[r] = vfma2(wb, sb1, zz1[r]);
        }
    }
    float za[HH], zb[HH];
    #pragma unroll
    for (int r = 0; r < HH; ++r) {
        za[r] = zz0[r].x + zz0[r].y;
        zb[r] = zz1[r].x + zz1[r].y;
    }
    const float b2s = b2[0];
    float v0 = edge_mlp_tail(za, b1, W2, b2s) * (lrow[j0] + CEPS) * invtemp;
    float v1 = edge_mlp_tail(zb, b1, W2, b2s) * (lrow[j0 + 1] + CEPS) * invtemp;
    float m = wave_max(fmaxf(v0, v1));
    if ((tid & 63) == 0) red[tid >> 6] = m;
    __syncthreads();
    m = red[0];
    #pragma unroll
    for (int k = 1; k < 6; ++k) m = fmaxf(m, red[k]);
    float e0 = __expf(v0 - m), e1 = __expf(v1 - m);
    float sw = wave_sum(e0 + e1);
    if ((tid & 63) == 0) red[8 + (tid >> 6)] = sw;
    __syncthreads();
    float ssum = 0.f;
    #pragma unroll
    for (int k = 0; k < 6; ++k) ssum += red[8 + k];
    const float inv = 1.f / ssum;
    float2 ov; ov.x = e0 * inv; ov.y = e1 * inv;
    *(float2*)&E2[(size_t)i * NN + j0] = ov;
    if (FUSE) {
        *(float2*)&ve2row[j0] = ov;
        __syncthreads();
        const int d = tid & 127, h = tid >> 7;  // h in 0..2
        v2f accp = {0.f, 0.f}, accx = {0.f, 0.f};
        const int k0 = h * 256;
        #pragma unroll 4
        for (int kk = 0; kk < 256; kk += 2) {
            const int k = k0 + kk;
            v2f sv; sv.x = S[(size_t)k * DD + d]; sv.y = S[(size_t)(k + 1) * DD + d];
            const v2f sev = *(const v2f*)&aux[k];
            const v2f vev = *(const v2f*)&ve2row[k];
            accp = vfma2(sev, sv, accp);
            accx = vfma2(vev, sv, accx);
        }
        partp[h][d] = accp.x + accp.y;
        partx[h][d] = accx.x + accx.y;
        __syncthreads();
        float preg = 0.f;
        if (tid < DD) {
            preg = partp[0][d] + partp[1][d] + partp[2][d];
            const float x = partx[0][d] + partx[1][d] + partx[2][d];
            qvv[d] = preg + x;
        }
        __syncthreads();
        if (tid < 256) {
            const int hh = tid >> 7;  // 0,1
            v2f acc; acc.x = (hh == 0) ? nb[d] : 0.f; acc.y = 0.f;
            const int c0 = hh * 64;
            #pragma unroll 4
            for (int c = c0; c < c0 + 64; c += 2) {
                v2f wv; wv.x = WT[(size_t)c * DD + d]; wv.y = WT[(size_t)(c + 1) * DD + d];
                const v2f qq = *(const v2f*)&qvv[c];
                acc = vfma2(qq, wv, acc);
            }
            partx[hh][d] = acc.x + acc.y;
        }
        __syncthreads();
        float tval = 0.f;
        if (tid < DD) {
            tval = partx[0][d] + partx[1][d];
            float sm2 = wave_sum(tval);
            if ((tid & 63) == 0) red[tid >> 6] = sm2;
        }
        __syncthreads();
        if (tid < DD) {
            const float mean = (red[0] + red[1]) * (1.f / DD);
            const float dv = tval - mean;
            float s2 = wave_sum(dv * dv);
            if ((tid & 63) == 0) red[8 + (tid >> 6)] = s2;
        }
        __syncthreads();
        if (tid < DD) {
            const float mean = (red[0] + red[1]) * (1.f / DD);
            const float var = (red[8] + red[9]) * (1.f / DD);
            const float ln = (tval - mean) * rsqrtf(var + 1e-5f) * ng[d] + nbeta[d];
            const float val = fmaxf(ln, 0.f) + preg;
            outN[(size_t)i * DD + d] = val;
            outNT[(size_t)d * NN + i] = val;
        }
    }
}

extern "C" void kernel_launch(void* const* d_in, const int* in_sizes, int n_in, void* d_out,
                              int out_size, void* d_ws, size_t ws_size, hipStream_t stream) {
    const float* visual    = (const float*)d_in[0];
    const float* semantic  = (const float*)d_in[1];
    const float* attribute = (const float*)d_in[2];
    const float* Wvn  = (const float*)d_in[3];
    const float* bvn  = (const float*)d_in[4];
    const float* gvn  = (const float*)d_in[5];
    const float* betavn = (const float*)d_in[6];
    const float* Wve1 = (const float*)d_in[7];
    const float* bve1 = (const float*)d_in[8];
    const float* Wve2 = (const float*)d_in[9];
    const float* bve2 = (const float*)d_in[10];
    const float* Wsn  = (const float*)d_in[11];
    const float* bsn  = (const float*)d_in[12];
    const float* gsn  = (const float*)d_in[13];
    const float* betasn = (const float*)d_in[14];
    const float* Wse1 = (const float*)d_in[15];
    const float* bse1 = (const float*)d_in[16];
    const float* Wse2 = (const float*)d_in[17];
    const float* bse2 = (const float*)d_in[18];

    float* out = (float*)d_out;
    float* vp  = out;              // 768*128
    float* sp  = out + 98304;      // 768*128
    float* ve2 = out + 196608;     // 768*768
    float* se2 = out + 786432;     // 768*768

    float* ws   = (float*)d_ws;
    float* simv = ws;              // 768*768 raw logits (already /temp)
    float* sima = ws + 589824;     // 768*768
    float* vpT  = ws + 1179648;    // 128*768
    float* spT  = ws + 1277952;    // 128*768
    float* WvnT = ws + 1376256;    // 128*128
    float* WsnT = ws + 1392640;    // 128*128

    gram_prep_kernel<<<1184, 256, 0, stream>>>(visual, attribute, Wvn, Wsn, simv, sima, WvnT,
                                               WsnT);
    node1_kernel<<<NN / 2, 512, 0, stream>>>(visual, simv, sima, WvnT, bvn, gvn, betavn, vp,
                                             vpT);
    // K3: edge1 (ve2) fused with node2 (sp, spT)
    edge_fused_kernel<true><<<NN, 384, 0, stream>>>(vp, vpT, simv, Wve1, bve1, Wve2, bve2,
                                                    0.1f, ve2, sima, semantic, WsnT, bsn, gsn,
                                                    betasn, sp, spT);
    // K4: edge2 (se2)
    edge_fused_kernel<false><<<NN, 384, 0, stream>>>(sp, spT, sima, Wse1, bse1, Wse2, bse2,
                                                     0.1f, se2, sima, semantic, WsnT, bsn, gsn,
                                                     betasn, nullptr, nullptr);
}